// Round 1
// baseline (1580.307 us; speedup 1.0000x reference)
//
#include <hip/hip_runtime.h>
#include <math.h>

#define IDIM 512
#define HDIM 64

// ---- degree: deg[dst] += 1 over edges ----
__global__ __launch_bounds__(256) void k_deg(const int* __restrict__ dst,
                                             float* __restrict__ deg, int E) {
    int e = blockIdx.x * blockDim.x + threadIdx.x;
    if (e < E) atomicAdd(&deg[dst[e]], 1.0f);
}

// ---- dinv = rsqrt(deg + 1) in place ----
__global__ __launch_bounds__(256) void k_dinv(float* __restrict__ deg, int n) {
    int i = blockIdx.x * blockDim.x + threadIdx.x;
    if (i < n) deg[i] = rsqrtf(deg[i] + 1.0f);
}

// ---- xw = x @ W1 : [n,512] x [512,64] ----
// 256 threads per block, 4 rows per block. x rows staged in LDS.
__global__ __launch_bounds__(256) void k_gemm1(const float* __restrict__ x,
                                               const float* __restrict__ W1,
                                               float* __restrict__ xw, int n) {
    __shared__ float xs[4][IDIM];
    int row0 = blockIdx.x * 4;
    int tid = threadIdx.x;
    int nrows = n - row0; if (nrows > 4) nrows = 4;
    if (nrows <= 0) return;
    const float4* xg = (const float4*)(x + (size_t)row0 * IDIM);
    float4* xs4 = (float4*)&xs[0][0];
    int nf4 = nrows * (IDIM / 4);
    for (int i = tid; i < nf4; i += 256) xs4[i] = xg[i];
    __syncthreads();
    int r = tid >> 6;
    int t = tid & 63;
    if (r >= nrows) return;
    const float* xr = &xs[r][0];
    float acc = 0.f;
#pragma unroll 4
    for (int k = 0; k < IDIM; k += 4) {
        float4 xv = *(const float4*)(xr + k);   // LDS broadcast within wave
        acc += xv.x * W1[(k + 0) * HDIM + t];
        acc += xv.y * W1[(k + 1) * HDIM + t];
        acc += xv.z * W1[(k + 2) * HDIM + t];
        acc += xv.w * W1[(k + 3) * HDIM + t];
    }
    xw[(size_t)(row0 + r) * HDIM + t] = acc;
}

// ---- agg[dst] += feat[src] * dinv[src]*dinv[dst], one thread per (edge,feature) ----
__global__ __launch_bounds__(256) void k_scatter(const int* __restrict__ src,
                                                 const int* __restrict__ dst,
                                                 const float* __restrict__ dinv,
                                                 const float* __restrict__ feat,
                                                 float* __restrict__ agg, int E) {
    int idx = blockIdx.x * blockDim.x + threadIdx.x;
    int e = idx >> 6;
    if (e >= E) return;
    int f = idx & 63;
    int s = src[e], d = dst[e];
    float w = dinv[s] * dinv[d];
    float v = feat[(size_t)s * HDIM + f] * w;
    atomicAdd(&agg[(size_t)d * HDIM + f], v);
}

// ---- h = relu(agg + xw*dinv^2 + b1), in place into agg buffer ----
__global__ __launch_bounds__(256) void k_post1(const float* __restrict__ xw,
                                               float* __restrict__ agg,
                                               const float* __restrict__ dinv,
                                               const float* __restrict__ b1, int n) {
    int idx = blockIdx.x * blockDim.x + threadIdx.x;
    if (idx >= n * HDIM) return;
    int i = idx >> 6, f = idx & 63;
    float di = dinv[i];
    float v = agg[idx] + xw[idx] * di * di + b1[f];
    agg[idx] = fmaxf(v, 0.f);
}

// ---- epilogue: per node, agg2 full row -> z_mean / z_var / z ----
__global__ __launch_bounds__(256) void k_final(const float* __restrict__ agg2,
                                               const float* __restrict__ h,
                                               const float* __restrict__ dinv,
                                               const float* __restrict__ Wmu,
                                               const float* __restrict__ bmu,
                                               const float* __restrict__ Wvar,
                                               const float* __restrict__ bvar,
                                               const float* __restrict__ eps,
                                               float* __restrict__ out, int n) {
    __shared__ float s[4][HDIM];
    int row0 = blockIdx.x * 4;
    int tid = threadIdx.x;
    int r = tid >> 6, t = tid & 63;
    int i = row0 + r;
    if (i < n) {
        float di = dinv[i];
        s[r][t] = agg2[(size_t)i * HDIM + t] + h[(size_t)i * HDIM + t] * di * di;
    }
    __syncthreads();
    if (i >= n) return;
    float am = bmu[t], av = bvar[t];
    const float* sr = &s[r][0];
#pragma unroll 8
    for (int k = 0; k < HDIM; k++) {
        float hv = sr[k];
        am += hv * Wmu[k * HDIM + t];
        av += hv * Wvar[k * HDIM + t];
    }
    // softplus, numerically stable
    float zv = fmaxf(av, 0.f) + log1pf(expf(-fabsf(av)));
    float zm = am;
    float z = zm + zv * eps[(size_t)i * HDIM + t];
    size_t o = (size_t)i * HDIM + t;
    size_t nh = (size_t)n * HDIM;
    out[o] = zm;
    out[nh + o] = zv;
    out[2 * nh + o] = z;
}

extern "C" void kernel_launch(void* const* d_in, const int* in_sizes, int n_in,
                              void* d_out, int out_size, void* d_ws, size_t ws_size,
                              hipStream_t stream) {
    const float* x    = (const float*)d_in[0];
    const int*   ei   = (const int*)d_in[1];
    const float* W1   = (const float*)d_in[2];
    const float* b1   = (const float*)d_in[3];
    const float* Wmu  = (const float*)d_in[4];
    const float* bmu  = (const float*)d_in[5];
    const float* Wvar = (const float*)d_in[6];
    const float* bvar = (const float*)d_in[7];
    const float* eps  = (const float*)d_in[8];
    float* out = (float*)d_out;

    int n = in_sizes[0] / IDIM;
    int E = in_sizes[1] / 2;
    const int* src = ei;
    const int* dst = ei + E;

    // workspace layout: bufA [n*64] | bufB [n*64] | dinv [n]
    float* bufA = (float*)d_ws;                 // xw, later agg2
    float* bufB = bufA + (size_t)n * HDIM;      // agg1, later h
    float* dinv = bufB + (size_t)n * HDIM;

    size_t featBytes = (size_t)n * HDIM * sizeof(float);

    // 1. degree -> dinv
    hipMemsetAsync(dinv, 0, (size_t)n * sizeof(float), stream);
    k_deg<<<(E + 255) / 256, 256, 0, stream>>>(dst, dinv, E);
    k_dinv<<<(n + 255) / 256, 256, 0, stream>>>(dinv, n);

    // 2. xw = x @ W1  -> bufA
    k_gemm1<<<(n + 3) / 4, 256, 0, stream>>>(x, W1, bufA, n);

    // 3. agg1 = scatter(xw) -> bufB
    hipMemsetAsync(bufB, 0, featBytes, stream);
    {
        long long tot = (long long)E * HDIM;
        int blocks = (int)((tot + 255) / 256);
        k_scatter<<<blocks, 256, 0, stream>>>(src, dst, dinv, bufA, bufB, E);
    }

    // 4. h = relu(agg1 + xw*dinv^2 + b1), in place in bufB
    k_post1<<<(n * HDIM + 255) / 256, 256, 0, stream>>>(bufA, bufB, dinv, b1, n);

    // 5. agg2 = scatter(h) -> bufA (xw dead now)
    hipMemsetAsync(bufA, 0, featBytes, stream);
    {
        long long tot = (long long)E * HDIM;
        int blocks = (int)((tot + 255) / 256);
        k_scatter<<<blocks, 256, 0, stream>>>(src, dst, dinv, bufB, bufA, E);
    }

    // 6. epilogue: two 64x64 GEMMs + softplus + reparam -> out
    k_final<<<(n + 3) / 4, 256, 0, stream>>>(bufA, bufB, dinv, Wmu, bmu, Wvar, bvar,
                                             eps, out, n);
}

// Round 2
// 853.566 us; speedup vs baseline: 1.8514x; 1.8514x over previous
//
#include <hip/hip_runtime.h>
#include <math.h>

#define IDIM 512
#define HDIM 64

// ============ CSR build ============

// deg[dst] += 1 (deg lives in `cursor` array initially)
__global__ __launch_bounds__(256) void k_deg(const int* __restrict__ dst,
                                             int* __restrict__ deg, int E) {
    int e = blockIdx.x * blockDim.x + threadIdx.x;
    if (e < E) atomicAdd(&deg[dst[e]], 1);
}

// per-1024-chunk sums of deg
__global__ __launch_bounds__(256) void k_blocksum(const int* __restrict__ deg,
                                                  int* __restrict__ bsum, int n) {
    __shared__ int sd[256];
    int b = blockIdx.x, tid = threadIdx.x;
    int base = b * 1024 + tid * 4;
    int s = 0;
#pragma unroll
    for (int k = 0; k < 4; k++) {
        int idx = base + k;
        if (idx < n) s += deg[idx];
    }
    sd[tid] = s;
    __syncthreads();
    for (int off = 128; off > 0; off >>= 1) {
        if (tid < off) sd[tid] += sd[tid + off];
        __syncthreads();
    }
    if (tid == 0) bsum[b] = sd[0];
}

// serial exclusive scan of ~98 chunk sums; also rowptr[n] = E
__global__ void k_scanbsum(const int* __restrict__ bsum, int* __restrict__ boff,
                           int B, int* __restrict__ rowptr, int n, int E) {
    if (threadIdx.x == 0 && blockIdx.x == 0) {
        int acc = 0;
        for (int i = 0; i < B; i++) { boff[i] = acc; acc += bsum[i]; }
        rowptr[n] = E;
    }
}

// intra-chunk scan -> rowptr, cursor copy, dinv = rsqrt(deg+1)
__global__ __launch_bounds__(256) void k_rowptr(const int* __restrict__ deg,
                                                const int* __restrict__ boff,
                                                int* __restrict__ rowptr,
                                                int* __restrict__ cursor,
                                                float* __restrict__ dinv, int n) {
    __shared__ int sd[256];
    int b = blockIdx.x, tid = threadIdx.x;
    int base = b * 1024 + tid * 4;
    int d[4];
    int tt = 0;
#pragma unroll
    for (int k = 0; k < 4; k++) {
        d[k] = (base + k < n) ? deg[base + k] : 0;
        tt += d[k];
    }
    sd[tid] = tt;
    __syncthreads();
    for (int off = 1; off < 256; off <<= 1) {
        int v = 0;
        if (tid >= off) v = sd[tid - off];
        __syncthreads();
        sd[tid] += v;
        __syncthreads();
    }
    int run = boff[b] + sd[tid] - tt;  // exclusive prefix
#pragma unroll
    for (int k = 0; k < 4; k++) {
        if (base + k < n) {
            rowptr[base + k] = run;
            cursor[base + k] = run;
            dinv[base + k] = rsqrtf((float)d[k] + 1.0f);
            run += d[k];
        }
    }
}

// counting-sort: srcs[pos] = src[e], pos = cursor[dst[e]]++
__global__ __launch_bounds__(256) void k_build(const int* __restrict__ src,
                                               const int* __restrict__ dst,
                                               int* __restrict__ cursor,
                                               int* __restrict__ srcs, int E) {
    int e = blockIdx.x * blockDim.x + threadIdx.x;
    if (e >= E) return;
    int p = atomicAdd(&cursor[dst[e]], 1);
    srcs[p] = src[e];
}

// ============ GEMM1: g1 = (x @ W1) * dinv, register-blocked ============
// 16 rows/block, 256 threads = 4 waves, 4 rows per thread.
__global__ __launch_bounds__(256) void k_gemm1(const float* __restrict__ x,
                                               const float* __restrict__ W1,
                                               const float* __restrict__ dinv,
                                               float* __restrict__ g1, int n) {
    __shared__ float xs[16][IDIM];  // 32 KB
    int row0 = blockIdx.x * 16;
    int tid = threadIdx.x;
    // stage 16 rows of x (coalesced float4)
    const float4* xg = (const float4*)(x + (size_t)row0 * IDIM);
    float4* xs4 = (float4*)&xs[0][0];
    size_t lim4 = ((size_t)n * IDIM) / 4 - (size_t)row0 * (IDIM / 4);
#pragma unroll
    for (int i = 0; i < 8; i++) {
        int idx = tid + i * 256;
        if ((size_t)idx < lim4) xs4[idx] = xg[idx];
    }
    __syncthreads();
    int w = tid >> 6, t = tid & 63;
    int rbase = w * 4;
    float acc0 = 0.f, acc1 = 0.f, acc2 = 0.f, acc3 = 0.f;
    for (int k = 0; k < IDIM; k += 4) {
        float4 x0 = *(const float4*)&xs[rbase + 0][k];
        float4 x1 = *(const float4*)&xs[rbase + 1][k];
        float4 x2 = *(const float4*)&xs[rbase + 2][k];
        float4 x3 = *(const float4*)&xs[rbase + 3][k];
        float w0 = W1[(k + 0) * HDIM + t];
        float w1 = W1[(k + 1) * HDIM + t];
        float w2 = W1[(k + 2) * HDIM + t];
        float w3 = W1[(k + 3) * HDIM + t];
        acc0 += x0.x * w0 + x0.y * w1 + x0.z * w2 + x0.w * w3;
        acc1 += x1.x * w0 + x1.y * w1 + x1.z * w2 + x1.w * w3;
        acc2 += x2.x * w0 + x2.y * w1 + x2.z * w2 + x2.w * w3;
        acc3 += x3.x * w0 + x3.y * w1 + x3.z * w2 + x3.w * w3;
    }
    int r = row0 + rbase;
    if (r + 0 < n) g1[(size_t)(r + 0) * HDIM + t] = acc0 * dinv[r + 0];
    if (r + 1 < n) g1[(size_t)(r + 1) * HDIM + t] = acc1 * dinv[r + 1];
    if (r + 2 < n) g1[(size_t)(r + 2) * HDIM + t] = acc2 * dinv[r + 2];
    if (r + 3 < n) g1[(size_t)(r + 3) * HDIM + t] = acc3 * dinv[r + 3];
}

// ============ layer-1 gather: g2 = relu(dinv*(sum g1[src] + g1[i]) + b1) * dinv ====
__global__ __launch_bounds__(256) void k_gather1(const int* __restrict__ rowptr,
                                                 const int* __restrict__ srcs,
                                                 const float* __restrict__ dinv,
                                                 const float* __restrict__ g1,
                                                 const float* __restrict__ b1,
                                                 float* __restrict__ g2, int n) {
    int tid = threadIdx.x;
    int i = blockIdx.x * 4 + (tid >> 6);
    int t = tid & 63;
    if (i >= n) return;
    int beg = rowptr[i], end = rowptr[i + 1];
    float sum = 0.f;
    int j = beg;
    for (; j + 3 < end; j += 4) {
        int s0 = srcs[j], s1 = srcs[j + 1], s2 = srcs[j + 2], s3 = srcs[j + 3];
        float v0 = g1[(size_t)s0 * HDIM + t];
        float v1 = g1[(size_t)s1 * HDIM + t];
        float v2 = g1[(size_t)s2 * HDIM + t];
        float v3 = g1[(size_t)s3 * HDIM + t];
        sum += (v0 + v1) + (v2 + v3);
    }
    for (; j < end; j++) sum += g1[(size_t)srcs[j] * HDIM + t];
    float di = dinv[i];
    float h = fmaxf(di * (sum + g1[(size_t)i * HDIM + t]) + b1[t], 0.f);
    g2[(size_t)i * HDIM + t] = h * di;
}

// ============ layer-2 gather fused with epilogue ============
// a = dinv*(sum g2[src] + g2[i]); z_mean = a@Wmu+bmu; z_var = softplus(a@Wvar+bvar);
// z = z_mean + z_var*eps
__global__ __launch_bounds__(256) void k_gather2(const int* __restrict__ rowptr,
                                                 const int* __restrict__ srcs,
                                                 const float* __restrict__ dinv,
                                                 const float* __restrict__ g2,
                                                 const float* __restrict__ Wmu,
                                                 const float* __restrict__ bmu,
                                                 const float* __restrict__ Wvar,
                                                 const float* __restrict__ bvar,
                                                 const float* __restrict__ eps,
                                                 float* __restrict__ out, int n) {
    __shared__ float s[4][HDIM];
    int tid = threadIdx.x;
    int r = tid >> 6, t = tid & 63;
    int i = blockIdx.x * 4 + r;
    bool valid = (i < n);
    if (valid) {
        int beg = rowptr[i], end = rowptr[i + 1];
        float sum = 0.f;
        int j = beg;
        for (; j + 3 < end; j += 4) {
            int s0 = srcs[j], s1 = srcs[j + 1], s2 = srcs[j + 2], s3 = srcs[j + 3];
            float v0 = g2[(size_t)s0 * HDIM + t];
            float v1 = g2[(size_t)s1 * HDIM + t];
            float v2 = g2[(size_t)s2 * HDIM + t];
            float v3 = g2[(size_t)s3 * HDIM + t];
            sum += (v0 + v1) + (v2 + v3);
        }
        for (; j < end; j++) sum += g2[(size_t)srcs[j] * HDIM + t];
        s[r][t] = dinv[i] * (sum + g2[(size_t)i * HDIM + t]);
    }
    __syncthreads();
    if (!valid) return;
    float am = bmu[t], av = bvar[t];
    const float* sr = &s[r][0];
#pragma unroll 8
    for (int k = 0; k < HDIM; k++) {
        float hv = sr[k];
        am += hv * Wmu[k * HDIM + t];
        av += hv * Wvar[k * HDIM + t];
    }
    float zv = fmaxf(av, 0.f) + log1pf(expf(-fabsf(av)));
    float z = am + zv * eps[(size_t)i * HDIM + t];
    size_t o = (size_t)i * HDIM + t;
    size_t nh = (size_t)n * HDIM;
    out[o] = am;
    out[nh + o] = zv;
    out[2 * nh + o] = z;
}

extern "C" void kernel_launch(void* const* d_in, const int* in_sizes, int n_in,
                              void* d_out, int out_size, void* d_ws, size_t ws_size,
                              hipStream_t stream) {
    const float* x    = (const float*)d_in[0];
    const int*   ei   = (const int*)d_in[1];
    const float* W1   = (const float*)d_in[2];
    const float* b1   = (const float*)d_in[3];
    const float* Wmu  = (const float*)d_in[4];
    const float* bmu  = (const float*)d_in[5];
    const float* Wvar = (const float*)d_in[6];
    const float* bvar = (const float*)d_in[7];
    const float* eps  = (const float*)d_in[8];
    float* out = (float*)d_out;

    int n = in_sizes[0] / IDIM;
    int E = in_sizes[1] / 2;
    const int* src = ei;
    const int* dst = ei + E;

    // workspace layout
    float* bufA  = (float*)d_ws;                 // g1 [n*64]
    float* bufB  = bufA + (size_t)n * HDIM;      // g2 [n*64]
    float* dinv  = bufB + (size_t)n * HDIM;      // [n]
    int* rowptr  = (int*)(dinv + n);             // [n+1]
    int* cursor  = rowptr + (n + 1);             // [n] (deg first, then cursor)
    int* srcs    = cursor + n;                   // [E]
    int* bsum    = srcs + E;                     // [128]
    int* boff    = bsum + 128;                   // [128]

    int B = (n + 1023) / 1024;

    // --- CSR build ---
    hipMemsetAsync(cursor, 0, (size_t)n * sizeof(int), stream);
    k_deg<<<(E + 255) / 256, 256, 0, stream>>>(dst, cursor, E);
    k_blocksum<<<B, 256, 0, stream>>>(cursor, bsum, n);
    k_scanbsum<<<1, 64, 0, stream>>>(bsum, boff, B, rowptr, n, E);
    k_rowptr<<<B, 256, 0, stream>>>(cursor, boff, rowptr, cursor, dinv, n);
    k_build<<<(E + 255) / 256, 256, 0, stream>>>(src, dst, cursor, srcs, E);

    // --- layer 1 ---
    k_gemm1<<<(n + 15) / 16, 256, 0, stream>>>(x, W1, dinv, bufA, n);
    k_gather1<<<(n + 3) / 4, 256, 0, stream>>>(rowptr, srcs, dinv, bufA, b1, bufB, n);

    // --- layer 2 + epilogue ---
    k_gather2<<<(n + 3) / 4, 256, 0, stream>>>(rowptr, srcs, dinv, bufB, Wmu, bmu,
                                               Wvar, bvar, eps, out, n);
}

// Round 3
// 761.989 us; speedup vs baseline: 2.0739x; 1.1202x over previous
//
#include <hip/hip_runtime.h>
#include <hip/hip_bf16.h>
#include <math.h>

#define IDIM 512
#define HDIM 64

typedef __attribute__((ext_vector_type(8))) short short8;   // 8 bf16 = 4 VGPRs
typedef __attribute__((ext_vector_type(4))) float f32x4;    // MFMA accum

// ============ CSR build ============

__global__ __launch_bounds__(256) void k_deg(const int* __restrict__ dst,
                                             int* __restrict__ deg, int E) {
    int e = blockIdx.x * blockDim.x + threadIdx.x;
    if (e < E) atomicAdd(&deg[dst[e]], 1);
}

__global__ __launch_bounds__(256) void k_blocksum(const int* __restrict__ deg,
                                                  int* __restrict__ bsum, int n) {
    __shared__ int sd[256];
    int b = blockIdx.x, tid = threadIdx.x;
    int base = b * 1024 + tid * 4;
    int s = 0;
#pragma unroll
    for (int k = 0; k < 4; k++) {
        int idx = base + k;
        if (idx < n) s += deg[idx];
    }
    sd[tid] = s;
    __syncthreads();
    for (int off = 128; off > 0; off >>= 1) {
        if (tid < off) sd[tid] += sd[tid + off];
        __syncthreads();
    }
    if (tid == 0) bsum[b] = sd[0];
}

// parallel exclusive scan of B<=128 chunk sums (one block)
__global__ __launch_bounds__(128) void k_scanbsum(const int* __restrict__ bsum,
                                                  int* __restrict__ boff, int B,
                                                  int* __restrict__ rowptr, int n, int E) {
    __shared__ int s[128];
    int t = threadIdx.x;
    int v = (t < B) ? bsum[t] : 0;
    s[t] = v;
    __syncthreads();
    for (int off = 1; off < 128; off <<= 1) {
        int u = (t >= off) ? s[t - off] : 0;
        __syncthreads();
        s[t] += u;
        __syncthreads();
    }
    if (t < B) boff[t] = s[t] - v;  // exclusive prefix
    if (t == 0) rowptr[n] = E;
}

__global__ __launch_bounds__(256) void k_rowptr(const int* __restrict__ deg,
                                                const int* __restrict__ boff,
                                                int* __restrict__ rowptr,
                                                int* __restrict__ cursor,
                                                float* __restrict__ dinv, int n) {
    __shared__ int sd[256];
    int b = blockIdx.x, tid = threadIdx.x;
    int base = b * 1024 + tid * 4;
    int d[4];
    int tt = 0;
#pragma unroll
    for (int k = 0; k < 4; k++) {
        d[k] = (base + k < n) ? deg[base + k] : 0;
        tt += d[k];
    }
    sd[tid] = tt;
    __syncthreads();
    for (int off = 1; off < 256; off <<= 1) {
        int v = 0;
        if (tid >= off) v = sd[tid - off];
        __syncthreads();
        sd[tid] += v;
        __syncthreads();
    }
    int run = boff[b] + sd[tid] - tt;
#pragma unroll
    for (int k = 0; k < 4; k++) {
        if (base + k < n) {
            rowptr[base + k] = run;
            cursor[base + k] = run;
            dinv[base + k] = rsqrtf((float)d[k] + 1.0f);
            run += d[k];
        }
    }
}

__global__ __launch_bounds__(256) void k_build(const int* __restrict__ src,
                                               const int* __restrict__ dst,
                                               int* __restrict__ cursor,
                                               int* __restrict__ srcs, int E) {
    int e = blockIdx.x * blockDim.x + threadIdx.x;
    if (e >= E) return;
    int p = atomicAdd(&cursor[dst[e]], 1);
    srcs[p] = src[e];
}

// ============ W1 -> bf16 B^T table: Btg[n][k], n=0..63, k=0..511 ============
__global__ __launch_bounds__(256) void k_prepB(const float* __restrict__ W1,
                                               short* __restrict__ Btg) {
    int id = blockIdx.x * 256 + threadIdx.x;
    if (id >= IDIM * HDIM) return;
    int k = id >> 6, nn = id & 63;
    __hip_bfloat16 b = __float2bfloat16(W1[id]);
    Btg[nn * IDIM + k] = *(short*)&b;
}

// ============ GEMM1 (bf16 MFMA): g1 = (x @ W1) * dinv ============
// Block: 128 rows, 4 waves; wave: 32 rows x 64 cols; K-chunks of 128.
#define GM 128
#define KC 128
#define APAD 8
__global__ __launch_bounds__(256) void k_gemm1(const float* __restrict__ x,
                                               const short* __restrict__ Btg,
                                               const float* __restrict__ dinv,
                                               float* __restrict__ g1, int n) {
    __shared__ short As[GM][KC + APAD];    // 34.8 KB
    __shared__ short Bs[HDIM][KC + APAD];  // 17.4 KB
    int tid = threadIdx.x;
    int row0 = blockIdx.x * GM;
    int w = tid >> 6, lane = tid & 63;
    int m = lane & 15, kb = lane >> 4;

    f32x4 acc[2][4];
#pragma unroll
    for (int rb = 0; rb < 2; rb++)
#pragma unroll
        for (int nt = 0; nt < 4; nt++) acc[rb][nt] = (f32x4){0.f, 0.f, 0.f, 0.f};

    for (int kc = 0; kc < IDIM; kc += KC) {
        __syncthreads();
        // stage A: 128 rows x 128 k fp32 -> bf16 LDS (16 float4 / thread)
#pragma unroll
        for (int i = 0; i < 16; i++) {
            int idx = tid + i * 256;
            int r = idx >> 5;       // 32 float4 per row
            int c4 = idx & 31;
            int grow = row0 + r;
            float4 v = make_float4(0.f, 0.f, 0.f, 0.f);
            if (grow < n) v = *(const float4*)&x[(size_t)grow * IDIM + kc + c4 * 4];
            __hip_bfloat162 h0 = __float22bfloat162_rn(make_float2(v.x, v.y));
            __hip_bfloat162 h1 = __float22bfloat162_rn(make_float2(v.z, v.w));
            int2 p;
            p.x = *(int*)&h0;
            p.y = *(int*)&h1;
            *(int2*)&As[r][c4 * 4] = p;
        }
        // stage B: 64 rows x 128 k bf16 (4 x 16B / thread)
#pragma unroll
        for (int i = 0; i < 4; i++) {
            int idx = tid + i * 256;
            int r = idx >> 4;       // 16 x 16B chunks per row
            int u8 = idx & 15;
            float4 v = *(const float4*)&Btg[(size_t)r * IDIM + kc + u8 * 8];
            *(float4*)&Bs[r][u8 * 8] = v;
        }
        __syncthreads();
#pragma unroll
        for (int ks = 0; ks < KC; ks += 32) {
            short8 a0 = *(const short8*)&As[w * 32 + m][ks + kb * 8];
            short8 a1 = *(const short8*)&As[w * 32 + 16 + m][ks + kb * 8];
            short8 b0 = *(const short8*)&Bs[m][ks + kb * 8];
            short8 b1 = *(const short8*)&Bs[16 + m][ks + kb * 8];
            short8 b2 = *(const short8*)&Bs[32 + m][ks + kb * 8];
            short8 b3 = *(const short8*)&Bs[48 + m][ks + kb * 8];
            acc[0][0] = __builtin_amdgcn_mfma_f32_16x16x32_bf16(a0, b0, acc[0][0], 0, 0, 0);
            acc[0][1] = __builtin_amdgcn_mfma_f32_16x16x32_bf16(a0, b1, acc[0][1], 0, 0, 0);
            acc[0][2] = __builtin_amdgcn_mfma_f32_16x16x32_bf16(a0, b2, acc[0][2], 0, 0, 0);
            acc[0][3] = __builtin_amdgcn_mfma_f32_16x16x32_bf16(a0, b3, acc[0][3], 0, 0, 0);
            acc[1][0] = __builtin_amdgcn_mfma_f32_16x16x32_bf16(a1, b0, acc[1][0], 0, 0, 0);
            acc[1][1] = __builtin_amdgcn_mfma_f32_16x16x32_bf16(a1, b1, acc[1][1], 0, 0, 0);
            acc[1][2] = __builtin_amdgcn_mfma_f32_16x16x32_bf16(a1, b2, acc[1][2], 0, 0, 0);
            acc[1][3] = __builtin_amdgcn_mfma_f32_16x16x32_bf16(a1, b3, acc[1][3], 0, 0, 0);
        }
    }
    // epilogue: C/D layout col=lane&15 (m), row=(lane>>4)*4+reg
#pragma unroll
    for (int rb = 0; rb < 2; rb++) {
        int rbase = row0 + w * 32 + rb * 16 + kb * 4;
#pragma unroll
        for (int reg = 0; reg < 4; reg++) {
            int grow = rbase + reg;
            if (grow < n) {
                float dv = dinv[grow];
#pragma unroll
                for (int nt = 0; nt < 4; nt++)
                    g1[(size_t)grow * HDIM + nt * 16 + m] = acc[rb][nt][reg] * dv;
            }
        }
    }
}

// ============ layer-1 gather: g2 = relu(dinv*(sum g1[src] + g1[i]) + b1) * dinv ====
// wave per node; 4 lane-groups of 16, each group = one edge, lane&15 = float4 chunk
__global__ __launch_bounds__(256) void k_gather1(const int* __restrict__ rowptr,
                                                 const int* __restrict__ srcs,
                                                 const float* __restrict__ dinv,
                                                 const float* __restrict__ g1,
                                                 const float* __restrict__ b1,
                                                 float* __restrict__ g2, int n) {
    int tid = threadIdx.x;
    int r = tid >> 6, lane = tid & 63;
    int grp = lane >> 4, q = lane & 15;
    int i = blockIdx.x * 4 + r;
    if (i >= n) return;
    int beg = rowptr[i], end = rowptr[i + 1];
    float4 acc = make_float4(0.f, 0.f, 0.f, 0.f);
    int j = beg + grp;
    for (; j + 4 < end; j += 8) {
        int s0 = srcs[j];
        int s1 = srcs[j + 4];
        float4 v0 = *(const float4*)&g1[(size_t)s0 * HDIM + q * 4];
        float4 v1 = *(const float4*)&g1[(size_t)s1 * HDIM + q * 4];
        acc.x += v0.x + v1.x; acc.y += v0.y + v1.y;
        acc.z += v0.z + v1.z; acc.w += v0.w + v1.w;
    }
    if (j < end) {
        int s0 = srcs[j];
        float4 v0 = *(const float4*)&g1[(size_t)s0 * HDIM + q * 4];
        acc.x += v0.x; acc.y += v0.y; acc.z += v0.z; acc.w += v0.w;
    }
    acc.x += __shfl_xor(acc.x, 16); acc.y += __shfl_xor(acc.y, 16);
    acc.z += __shfl_xor(acc.z, 16); acc.w += __shfl_xor(acc.w, 16);
    acc.x += __shfl_xor(acc.x, 32); acc.y += __shfl_xor(acc.y, 32);
    acc.z += __shfl_xor(acc.z, 32); acc.w += __shfl_xor(acc.w, 32);
    if (grp == 0) {
        float4 self = *(const float4*)&g1[(size_t)i * HDIM + q * 4];
        float4 bv = *(const float4*)&b1[q * 4];
        float di = dinv[i];
        float4 o;
        o.x = fmaxf(di * (acc.x + self.x) + bv.x, 0.f) * di;
        o.y = fmaxf(di * (acc.y + self.y) + bv.y, 0.f) * di;
        o.z = fmaxf(di * (acc.z + self.z) + bv.z, 0.f) * di;
        o.w = fmaxf(di * (acc.w + self.w) + bv.w, 0.f) * di;
        *(float4*)&g2[(size_t)i * HDIM + q * 4] = o;
    }
}

// ============ layer-2 gather + epilogue ============
__global__ __launch_bounds__(256) void k_gather2(const int* __restrict__ rowptr,
                                                 const int* __restrict__ srcs,
                                                 const float* __restrict__ dinv,
                                                 const float* __restrict__ g2,
                                                 const float* __restrict__ Wmu,
                                                 const float* __restrict__ bmu,
                                                 const float* __restrict__ Wvar,
                                                 const float* __restrict__ bvar,
                                                 const float* __restrict__ eps,
                                                 float* __restrict__ out, int n) {
    __shared__ float sh[4][HDIM];
    int tid = threadIdx.x;
    int r = tid >> 6, lane = tid & 63;
    int grp = lane >> 4, q = lane & 15;
    int i = blockIdx.x * 4 + r;
    bool valid = (i < n);
    if (valid) {
        int beg = rowptr[i], end = rowptr[i + 1];
        float4 acc = make_float4(0.f, 0.f, 0.f, 0.f);
        int j = beg + grp;
        for (; j + 4 < end; j += 8) {
            int s0 = srcs[j];
            int s1 = srcs[j + 4];
            float4 v0 = *(const float4*)&g2[(size_t)s0 * HDIM + q * 4];
            float4 v1 = *(const float4*)&g2[(size_t)s1 * HDIM + q * 4];
            acc.x += v0.x + v1.x; acc.y += v0.y + v1.y;
            acc.z += v0.z + v1.z; acc.w += v0.w + v1.w;
        }
        if (j < end) {
            int s0 = srcs[j];
            float4 v0 = *(const float4*)&g2[(size_t)s0 * HDIM + q * 4];
            acc.x += v0.x; acc.y += v0.y; acc.z += v0.z; acc.w += v0.w;
        }
        acc.x += __shfl_xor(acc.x, 16); acc.y += __shfl_xor(acc.y, 16);
        acc.z += __shfl_xor(acc.z, 16); acc.w += __shfl_xor(acc.w, 16);
        acc.x += __shfl_xor(acc.x, 32); acc.y += __shfl_xor(acc.y, 32);
        acc.z += __shfl_xor(acc.z, 32); acc.w += __shfl_xor(acc.w, 32);
        if (grp == 0) {
            float4 self = *(const float4*)&g2[(size_t)i * HDIM + q * 4];
            float di = dinv[i];
            float4 o;
            o.x = di * (acc.x + self.x);
            o.y = di * (acc.y + self.y);
            o.z = di * (acc.z + self.z);
            o.w = di * (acc.w + self.w);
            *(float4*)&sh[r][q * 4] = o;
        }
    }
    __syncthreads();
    if (!valid) return;
    int t = lane;
    float am = bmu[t], av = bvar[t];
    const float* sr = &sh[r][0];
#pragma unroll 8
    for (int k = 0; k < HDIM; k++) {
        float hv = sr[k];
        am += hv * Wmu[k * HDIM + t];
        av += hv * Wvar[k * HDIM + t];
    }
    float zv = fmaxf(av, 0.f) + log1pf(expf(-fabsf(av)));
    float z = am + zv * eps[(size_t)i * HDIM + t];
    size_t o = (size_t)i * HDIM + t;
    size_t nh = (size_t)n * HDIM;
    out[o] = am;
    out[nh + o] = zv;
    out[2 * nh + o] = z;
}

extern "C" void kernel_launch(void* const* d_in, const int* in_sizes, int n_in,
                              void* d_out, int out_size, void* d_ws, size_t ws_size,
                              hipStream_t stream) {
    const float* x    = (const float*)d_in[0];
    const int*   ei   = (const int*)d_in[1];
    const float* W1   = (const float*)d_in[2];
    const float* b1   = (const float*)d_in[3];
    const float* Wmu  = (const float*)d_in[4];
    const float* bmu  = (const float*)d_in[5];
    const float* Wvar = (const float*)d_in[6];
    const float* bvar = (const float*)d_in[7];
    const float* eps  = (const float*)d_in[8];
    float* out = (float*)d_out;

    int n = in_sizes[0] / IDIM;
    int E = in_sizes[1] / 2;
    const int* src = ei;
    const int* dst = ei + E;

    // workspace layout
    float* bufA  = (float*)d_ws;                 // g1 [n*64]
    float* bufB  = bufA + (size_t)n * HDIM;      // g2 [n*64]
    float* dinv  = bufB + (size_t)n * HDIM;      // [n]
    int* rowptr  = (int*)(dinv + n);             // [n+1]
    int* cursor  = rowptr + (n + 1);             // [n]
    int* srcs    = cursor + n;                   // [E]
    int* bsum    = srcs + E;                     // [128]
    int* boff    = bsum + 128;                   // [128]
    short* Btg   = (short*)(boff + 128);         // [64*512] bf16 W1^T

    int B = (n + 1023) / 1024;

    // --- CSR build ---
    hipMemsetAsync(cursor, 0, (size_t)n * sizeof(int), stream);
    k_deg<<<(E + 255) / 256, 256, 0, stream>>>(dst, cursor, E);
    k_blocksum<<<B, 256, 0, stream>>>(cursor, bsum, n);
    k_scanbsum<<<1, 128, 0, stream>>>(bsum, boff, B, rowptr, n, E);
    k_rowptr<<<B, 256, 0, stream>>>(cursor, boff, rowptr, cursor, dinv, n);
    k_build<<<(E + 255) / 256, 256, 0, stream>>>(src, dst, cursor, srcs, E);

    // --- layer 1 ---
    k_prepB<<<(IDIM * HDIM + 255) / 256, 256, 0, stream>>>(W1, Btg);
    k_gemm1<<<(n + GM - 1) / GM, 256, 0, stream>>>(x, Btg, dinv, bufA, n);
    k_gather1<<<(n + 3) / 4, 256, 0, stream>>>(rowptr, srcs, dinv, bufA, b1, bufB, n);

    // --- layer 2 + epilogue ---
    k_gather2<<<(n + 3) / 4, 256, 0, stream>>>(rowptr, srcs, dinv, bufB, Wmu, bmu,
                                               Wvar, bvar, eps, out, n);
}

// Round 4
// 745.124 us; speedup vs baseline: 2.1209x; 1.0226x over previous
//
#include <hip/hip_runtime.h>
#include <hip/hip_bf16.h>
#include <math.h>

#define IDIM 512
#define HDIM 64

typedef __attribute__((ext_vector_type(8))) short short8;   // 8 bf16 = 4 VGPRs
typedef __attribute__((ext_vector_type(4))) float f32x4;    // MFMA accum
typedef unsigned short u16;
typedef unsigned int u32;

__device__ __forceinline__ float bflo(u32 u) { return __uint_as_float(u << 16); }
__device__ __forceinline__ float bfhi(u32 u) { return __uint_as_float(u & 0xffff0000u); }

// ============ CSR build ============

__global__ __launch_bounds__(256) void k_deg(const int* __restrict__ dst,
                                             int* __restrict__ deg, int E) {
    int e = blockIdx.x * blockDim.x + threadIdx.x;
    if (e < E) atomicAdd(&deg[dst[e]], 1);
}

__global__ __launch_bounds__(256) void k_blocksum(const int* __restrict__ deg,
                                                  int* __restrict__ bsum, int n) {
    __shared__ int sd[256];
    int b = blockIdx.x, tid = threadIdx.x;
    int base = b * 1024 + tid * 4;
    int s = 0;
#pragma unroll
    for (int k = 0; k < 4; k++) {
        int idx = base + k;
        if (idx < n) s += deg[idx];
    }
    sd[tid] = s;
    __syncthreads();
    for (int off = 128; off > 0; off >>= 1) {
        if (tid < off) sd[tid] += sd[tid + off];
        __syncthreads();
    }
    if (tid == 0) bsum[b] = sd[0];
}

__global__ __launch_bounds__(128) void k_scanbsum(const int* __restrict__ bsum,
                                                  int* __restrict__ boff, int B,
                                                  int* __restrict__ rowptr, int n, int E) {
    __shared__ int s[128];
    int t = threadIdx.x;
    int v = (t < B) ? bsum[t] : 0;
    s[t] = v;
    __syncthreads();
    for (int off = 1; off < 128; off <<= 1) {
        int u = (t >= off) ? s[t - off] : 0;
        __syncthreads();
        s[t] += u;
        __syncthreads();
    }
    if (t < B) boff[t] = s[t] - v;
    if (t == 0) rowptr[n] = E;
}

__global__ __launch_bounds__(256) void k_rowptr(const int* __restrict__ deg,
                                                const int* __restrict__ boff,
                                                int* __restrict__ rowptr,
                                                int* __restrict__ cursor,
                                                float* __restrict__ dinv, int n) {
    __shared__ int sd[256];
    int b = blockIdx.x, tid = threadIdx.x;
    int base = b * 1024 + tid * 4;
    int d[4];
    int tt = 0;
#pragma unroll
    for (int k = 0; k < 4; k++) {
        d[k] = (base + k < n) ? deg[base + k] : 0;
        tt += d[k];
    }
    sd[tid] = tt;
    __syncthreads();
    for (int off = 1; off < 256; off <<= 1) {
        int v = 0;
        if (tid >= off) v = sd[tid - off];
        __syncthreads();
        sd[tid] += v;
        __syncthreads();
    }
    int run = boff[b] + sd[tid] - tt;
#pragma unroll
    for (int k = 0; k < 4; k++) {
        if (base + k < n) {
            rowptr[base + k] = run;
            cursor[base + k] = run;
            dinv[base + k] = rsqrtf((float)d[k] + 1.0f);
            run += d[k];
        }
    }
}

__global__ __launch_bounds__(256) void k_build(const int* __restrict__ src,
                                               const int* __restrict__ dst,
                                               int* __restrict__ cursor,
                                               int* __restrict__ srcs, int E) {
    int e = blockIdx.x * blockDim.x + threadIdx.x;
    if (e >= E) return;
    int p = atomicAdd(&cursor[dst[e]], 1);
    srcs[p] = src[e];
}

// ============ W1 -> bf16 B^T table ============
__global__ __launch_bounds__(256) void k_prepB(const float* __restrict__ W1,
                                               short* __restrict__ Btg) {
    int id = blockIdx.x * 256 + threadIdx.x;
    if (id >= IDIM * HDIM) return;
    int k = id >> 6, nn = id & 63;
    __hip_bfloat16 b = __float2bfloat16(W1[id]);
    Btg[nn * IDIM + k] = *(short*)&b;
}

// ============ GEMM1 (bf16 MFMA): g1 = bf16((x @ W1) * dinv) ============
#define GM 128
#define KC 128
#define APAD 8
__global__ __launch_bounds__(256) void k_gemm1(const float* __restrict__ x,
                                               const short* __restrict__ Btg,
                                               const float* __restrict__ dinv,
                                               u16* __restrict__ g1, int n) {
    __shared__ short As[GM][KC + APAD];
    __shared__ short Bs[HDIM][KC + APAD];
    int tid = threadIdx.x;
    int row0 = blockIdx.x * GM;
    int w = tid >> 6, lane = tid & 63;
    int m = lane & 15, kb = lane >> 4;

    f32x4 acc[2][4];
#pragma unroll
    for (int rb = 0; rb < 2; rb++)
#pragma unroll
        for (int nt = 0; nt < 4; nt++) acc[rb][nt] = (f32x4){0.f, 0.f, 0.f, 0.f};

    for (int kc = 0; kc < IDIM; kc += KC) {
        __syncthreads();
#pragma unroll
        for (int i = 0; i < 16; i++) {
            int idx = tid + i * 256;
            int r = idx >> 5;
            int c4 = idx & 31;
            int grow = row0 + r;
            float4 v = make_float4(0.f, 0.f, 0.f, 0.f);
            if (grow < n) v = *(const float4*)&x[(size_t)grow * IDIM + kc + c4 * 4];
            __hip_bfloat162 h0 = __float22bfloat162_rn(make_float2(v.x, v.y));
            __hip_bfloat162 h1 = __float22bfloat162_rn(make_float2(v.z, v.w));
            int2 p;
            p.x = *(int*)&h0;
            p.y = *(int*)&h1;
            *(int2*)&As[r][c4 * 4] = p;
        }
#pragma unroll
        for (int i = 0; i < 4; i++) {
            int idx = tid + i * 256;
            int r = idx >> 4;
            int u8 = idx & 15;
            float4 v = *(const float4*)&Btg[(size_t)r * IDIM + kc + u8 * 8];
            *(float4*)&Bs[r][u8 * 8] = v;
        }
        __syncthreads();
#pragma unroll
        for (int ks = 0; ks < KC; ks += 32) {
            short8 a0 = *(const short8*)&As[w * 32 + m][ks + kb * 8];
            short8 a1 = *(const short8*)&As[w * 32 + 16 + m][ks + kb * 8];
            short8 b0 = *(const short8*)&Bs[m][ks + kb * 8];
            short8 b1 = *(const short8*)&Bs[16 + m][ks + kb * 8];
            short8 b2 = *(const short8*)&Bs[32 + m][ks + kb * 8];
            short8 b3 = *(const short8*)&Bs[48 + m][ks + kb * 8];
            acc[0][0] = __builtin_amdgcn_mfma_f32_16x16x32_bf16(a0, b0, acc[0][0], 0, 0, 0);
            acc[0][1] = __builtin_amdgcn_mfma_f32_16x16x32_bf16(a0, b1, acc[0][1], 0, 0, 0);
            acc[0][2] = __builtin_amdgcn_mfma_f32_16x16x32_bf16(a0, b2, acc[0][2], 0, 0, 0);
            acc[0][3] = __builtin_amdgcn_mfma_f32_16x16x32_bf16(a0, b3, acc[0][3], 0, 0, 0);
            acc[1][0] = __builtin_amdgcn_mfma_f32_16x16x32_bf16(a1, b0, acc[1][0], 0, 0, 0);
            acc[1][1] = __builtin_amdgcn_mfma_f32_16x16x32_bf16(a1, b1, acc[1][1], 0, 0, 0);
            acc[1][2] = __builtin_amdgcn_mfma_f32_16x16x32_bf16(a1, b2, acc[1][2], 0, 0, 0);
            acc[1][3] = __builtin_amdgcn_mfma_f32_16x16x32_bf16(a1, b3, acc[1][3], 0, 0, 0);
        }
    }
#pragma unroll
    for (int rb = 0; rb < 2; rb++) {
        int rbase = row0 + w * 32 + rb * 16 + kb * 4;
#pragma unroll
        for (int reg = 0; reg < 4; reg++) {
            int grow = rbase + reg;
            if (grow < n) {
                float dv = dinv[grow];
#pragma unroll
                for (int nt = 0; nt < 4; nt++) {
                    __hip_bfloat16 b = __float2bfloat16(acc[rb][nt][reg] * dv);
                    g1[(size_t)grow * HDIM + nt * 16 + m] = *(u16*)&b;
                }
            }
        }
    }
}

// ============ layer-1 gather (bf16 tables) ============
// wave per node; 8 lane-groups of 8; lane&7 = 16B feature chunk (8 bf16)
__global__ __launch_bounds__(256) void k_gather1(const int* __restrict__ rowptr,
                                                 const int* __restrict__ srcs,
                                                 const float* __restrict__ dinv,
                                                 const u16* __restrict__ g1,
                                                 const float* __restrict__ b1,
                                                 u16* __restrict__ g2, int n) {
    int tid = threadIdx.x;
    int r = tid >> 6, lane = tid & 63;
    int grp = lane >> 3, q = lane & 7;
    int i = blockIdx.x * 4 + r;
    if (i >= n) return;
    int beg = rowptr[i], end = rowptr[i + 1];
    float a[8];
#pragma unroll
    for (int k = 0; k < 8; k++) a[k] = 0.f;
    int j = beg + grp;
    for (; j + 8 < end; j += 16) {
        int s0 = srcs[j];
        int s1 = srcs[j + 8];
        uint4 u0 = *(const uint4*)&g1[(size_t)s0 * HDIM + q * 8];
        uint4 u1 = *(const uint4*)&g1[(size_t)s1 * HDIM + q * 8];
        a[0] += bflo(u0.x) + bflo(u1.x); a[1] += bfhi(u0.x) + bfhi(u1.x);
        a[2] += bflo(u0.y) + bflo(u1.y); a[3] += bfhi(u0.y) + bfhi(u1.y);
        a[4] += bflo(u0.z) + bflo(u1.z); a[5] += bfhi(u0.z) + bfhi(u1.z);
        a[6] += bflo(u0.w) + bflo(u1.w); a[7] += bfhi(u0.w) + bfhi(u1.w);
    }
    if (j < end) {
        int s0 = srcs[j];
        uint4 u0 = *(const uint4*)&g1[(size_t)s0 * HDIM + q * 8];
        a[0] += bflo(u0.x); a[1] += bfhi(u0.x);
        a[2] += bflo(u0.y); a[3] += bfhi(u0.y);
        a[4] += bflo(u0.z); a[5] += bfhi(u0.z);
        a[6] += bflo(u0.w); a[7] += bfhi(u0.w);
    }
#pragma unroll
    for (int k = 0; k < 8; k++) {
        a[k] += __shfl_xor(a[k], 8);
        a[k] += __shfl_xor(a[k], 16);
        a[k] += __shfl_xor(a[k], 32);
    }
    if (grp == 0) {
        uint4 us = *(const uint4*)&g1[(size_t)i * HDIM + q * 8];
        float s0 = bflo(us.x), s1 = bfhi(us.x), s2 = bflo(us.y), s3 = bfhi(us.y);
        float s4 = bflo(us.z), s5 = bfhi(us.z), s6 = bflo(us.w), s7 = bfhi(us.w);
        float4 bv0 = *(const float4*)&b1[q * 8];
        float4 bv1 = *(const float4*)&b1[q * 8 + 4];
        float di = dinv[i];
        float o0 = fmaxf(di * (a[0] + s0) + bv0.x, 0.f) * di;
        float o1 = fmaxf(di * (a[1] + s1) + bv0.y, 0.f) * di;
        float o2 = fmaxf(di * (a[2] + s2) + bv0.z, 0.f) * di;
        float o3 = fmaxf(di * (a[3] + s3) + bv0.w, 0.f) * di;
        float o4 = fmaxf(di * (a[4] + s4) + bv1.x, 0.f) * di;
        float o5 = fmaxf(di * (a[5] + s5) + bv1.y, 0.f) * di;
        float o6 = fmaxf(di * (a[6] + s6) + bv1.z, 0.f) * di;
        float o7 = fmaxf(di * (a[7] + s7) + bv1.w, 0.f) * di;
        __hip_bfloat162 p0 = __float22bfloat162_rn(make_float2(o0, o1));
        __hip_bfloat162 p1 = __float22bfloat162_rn(make_float2(o2, o3));
        __hip_bfloat162 p2 = __float22bfloat162_rn(make_float2(o4, o5));
        __hip_bfloat162 p3 = __float22bfloat162_rn(make_float2(o6, o7));
        uint4 w;
        w.x = *(u32*)&p0; w.y = *(u32*)&p1; w.z = *(u32*)&p2; w.w = *(u32*)&p3;
        *(uint4*)&g2[(size_t)i * HDIM + q * 8] = w;
    }
}

// ============ layer-2 gather + fused epilogue ============
__global__ __launch_bounds__(256) void k_gather2(const int* __restrict__ rowptr,
                                                 const int* __restrict__ srcs,
                                                 const float* __restrict__ dinv,
                                                 const u16* __restrict__ g2,
                                                 const float* __restrict__ Wmu,
                                                 const float* __restrict__ bmu,
                                                 const float* __restrict__ Wvar,
                                                 const float* __restrict__ bvar,
                                                 const float* __restrict__ eps,
                                                 float* __restrict__ out, int n) {
    __shared__ float sh[4][HDIM];
    int tid = threadIdx.x;
    int r = tid >> 6, lane = tid & 63;
    int grp = lane >> 3, q = lane & 7;
    int i = blockIdx.x * 4 + r;
    bool valid = (i < n);
    if (valid) {
        int beg = rowptr[i], end = rowptr[i + 1];
        float a[8];
#pragma unroll
        for (int k = 0; k < 8; k++) a[k] = 0.f;
        int j = beg + grp;
        for (; j + 8 < end; j += 16) {
            int s0 = srcs[j];
            int s1 = srcs[j + 8];
            uint4 u0 = *(const uint4*)&g2[(size_t)s0 * HDIM + q * 8];
            uint4 u1 = *(const uint4*)&g2[(size_t)s1 * HDIM + q * 8];
            a[0] += bflo(u0.x) + bflo(u1.x); a[1] += bfhi(u0.x) + bfhi(u1.x);
            a[2] += bflo(u0.y) + bflo(u1.y); a[3] += bfhi(u0.y) + bfhi(u1.y);
            a[4] += bflo(u0.z) + bflo(u1.z); a[5] += bfhi(u0.z) + bfhi(u1.z);
            a[6] += bflo(u0.w) + bflo(u1.w); a[7] += bfhi(u0.w) + bfhi(u1.w);
        }
        if (j < end) {
            int s0 = srcs[j];
            uint4 u0 = *(const uint4*)&g2[(size_t)s0 * HDIM + q * 8];
            a[0] += bflo(u0.x); a[1] += bfhi(u0.x);
            a[2] += bflo(u0.y); a[3] += bfhi(u0.y);
            a[4] += bflo(u0.z); a[5] += bfhi(u0.z);
            a[6] += bflo(u0.w); a[7] += bfhi(u0.w);
        }
#pragma unroll
        for (int k = 0; k < 8; k++) {
            a[k] += __shfl_xor(a[k], 8);
            a[k] += __shfl_xor(a[k], 16);
            a[k] += __shfl_xor(a[k], 32);
        }
        if (grp == 0) {
            uint4 us = *(const uint4*)&g2[(size_t)i * HDIM + q * 8];
            float di = dinv[i];
            float4 o0, o1;
            o0.x = di * (a[0] + bflo(us.x));
            o0.y = di * (a[1] + bfhi(us.x));
            o0.z = di * (a[2] + bflo(us.y));
            o0.w = di * (a[3] + bfhi(us.y));
            o1.x = di * (a[4] + bflo(us.z));
            o1.y = di * (a[5] + bfhi(us.z));
            o1.z = di * (a[6] + bflo(us.w));
            o1.w = di * (a[7] + bfhi(us.w));
            *(float4*)&sh[r][q * 8] = o0;
            *(float4*)&sh[r][q * 8 + 4] = o1;
        }
    }
    __syncthreads();
    if (!valid) return;
    int t = lane;
    float am = bmu[t], av = bvar[t];
    const float* sr = &sh[r][0];
#pragma unroll 8
    for (int k = 0; k < HDIM; k++) {
        float hv = sr[k];
        am += hv * Wmu[k * HDIM + t];
        av += hv * Wvar[k * HDIM + t];
    }
    float zv = fmaxf(av, 0.f) + log1pf(expf(-fabsf(av)));
    float z = am + zv * eps[(size_t)i * HDIM + t];
    size_t o = (size_t)i * HDIM + t;
    size_t nh = (size_t)n * HDIM;
    out[o] = am;
    out[nh + o] = zv;
    out[2 * nh + o] = z;
}

extern "C" void kernel_launch(void* const* d_in, const int* in_sizes, int n_in,
                              void* d_out, int out_size, void* d_ws, size_t ws_size,
                              hipStream_t stream) {
    const float* x    = (const float*)d_in[0];
    const int*   ei   = (const int*)d_in[1];
    const float* W1   = (const float*)d_in[2];
    const float* b1   = (const float*)d_in[3];
    const float* Wmu  = (const float*)d_in[4];
    const float* bmu  = (const float*)d_in[5];
    const float* Wvar = (const float*)d_in[6];
    const float* bvar = (const float*)d_in[7];
    const float* eps  = (const float*)d_in[8];
    float* out = (float*)d_out;

    int n = in_sizes[0] / IDIM;
    int E = in_sizes[1] / 2;
    const int* src = ei;
    const int* dst = ei + E;

    // workspace layout
    u16* bufA    = (u16*)d_ws;                   // g1 [n*64] bf16
    u16* bufB    = bufA + (size_t)n * HDIM;      // g2 [n*64] bf16
    float* dinv  = (float*)(bufB + (size_t)n * HDIM);  // [n]
    int* rowptr  = (int*)(dinv + n);             // [n+1]
    int* cursor  = rowptr + (n + 1);             // [n]
    int* srcs    = cursor + n;                   // [E]
    int* bsum    = srcs + E;                     // [128]
    int* boff    = bsum + 128;                   // [128]
    short* Btg   = (short*)(boff + 128);         // [64*512] bf16 W1^T

    int B = (n + 1023) / 1024;

    // --- CSR build ---
    hipMemsetAsync(cursor, 0, (size_t)n * sizeof(int), stream);
    k_deg<<<(E + 255) / 256, 256, 0, stream>>>(dst, cursor, E);
    k_blocksum<<<B, 256, 0, stream>>>(cursor, bsum, n);
    k_scanbsum<<<1, 128, 0, stream>>>(bsum, boff, B, rowptr, n, E);
    k_rowptr<<<B, 256, 0, stream>>>(cursor, boff, rowptr, cursor, dinv, n);
    k_build<<<(E + 255) / 256, 256, 0, stream>>>(src, dst, cursor, srcs, E);

    // --- layer 1 ---
    k_prepB<<<(IDIM * HDIM + 255) / 256, 256, 0, stream>>>(W1, Btg);
    k_gemm1<<<(n + GM - 1) / GM, 256, 0, stream>>>(x, Btg, dinv, bufA, n);
    k_gather1<<<(n + 3) / 4, 256, 0, stream>>>(rowptr, srcs, dinv, bufA, b1, bufB, n);

    // --- layer 2 + epilogue ---
    k_gather2<<<(n + 3) / 4, 256, 0, stream>>>(rowptr, srcs, dinv, bufB, Wmu, bmu,
                                               Wvar, bvar, eps, out, n);
}